// Round 1
// 5725.305 us; speedup vs baseline: 1.2752x; 1.2752x over previous
//
#include <hip/hip_runtime.h>
#include <hip/hip_bf16.h>
#include <math.h>

#define Dn 12
#define Cc 768
#define NHh 12
#define HD 64
#define Gg 14
#define Nn_TOK 197
#define HID 3072
#define NC 1000
#define Bb 32

typedef __attribute__((ext_vector_type(8))) short short8;
typedef __attribute__((ext_vector_type(4))) float f32x4;

__device__ __forceinline__ ushort f2b(float v) {
    union { float f; unsigned u; } x; x.f = v;
    unsigned r = x.u + 0x7fff + ((x.u >> 16) & 1);
    return (ushort)(r >> 16);
}
__device__ __forceinline__ float b2f(ushort v) {
    union { unsigned u; float f; } x; x.u = ((unsigned)v) << 16; return x.f;
}
__device__ __forceinline__ void gld16(const void* g, void* s) {
    __builtin_amdgcn_global_load_lds(
        (const __attribute__((address_space(1))) void*)g,
        (__attribute__((address_space(3))) void*)s, 16, 0, 0);
}

// ---------------- im2col: x (B,3,224,224) fp32 -> xp (B,196,768) bf16 ----------------
__global__ void im2col_kernel(const float* __restrict__ x, ushort* __restrict__ xp) {
    size_t idx = (size_t)blockIdx.x * 256 + threadIdx.x;
    const size_t total = (size_t)Bb * 196 * 768;
    if (idx >= total) return;
    int j = idx % 768;
    size_t t0 = idx / 768;
    int g = t0 % 196;
    int b = t0 / 196;
    int ch = j / 256, rem = j % 256, pr = rem / 16, pc = rem % 16;
    int gr = g / Gg, gc = g % Gg;
    int row = gr * 16 + pr, col = gc * 16 + pc;
    xp[idx] = f2b(x[(((size_t)b * 3 + ch) * 224 + row) * 224 + col]);
}

// ---------------- assemble t = concat(cls, patches) + pos (fp32) ----------------
__global__ void assemble_kernel(const float* __restrict__ pe, const float* __restrict__ cls,
                                const float* __restrict__ pos, float* __restrict__ t) {
    size_t idx = (size_t)blockIdx.x * 256 + threadIdx.x;
    const size_t total = (size_t)Bb * Nn_TOK * 768;
    if (idx >= total) return;
    int c = idx % 768;
    size_t r = idx / 768;
    int n = r % Nn_TOK, b = r / Nn_TOK;
    float v;
    if (n == 0) v = cls[c];
    else       v = pe[((size_t)b * 196 + (n - 1)) * 768 + c];
    t[idx] = v + pos[(size_t)n * 768 + c];
}

// ---------------- elementwise fp32 -> bf16 convert ----------------
__global__ void cvt_kernel(const float* __restrict__ src, ushort* __restrict__ dst, int n) {
    int idx = blockIdx.x * 256 + threadIdx.x;
    if (idx < n) dst[idx] = f2b(src[idx]);
}

// ---------------- tiled transpose-convert: src (K,N) fp32 -> dst (N,K) bf16 ----------------
__global__ __launch_bounds__(256) void transpose_one(const float* __restrict__ src,
                                                     ushort* __restrict__ dst, int K, int N) {
    int k0 = blockIdx.x * 32, n0 = blockIdx.y * 32;
    __shared__ float tile[32][33];
    int tx = threadIdx.x & 31, ty = threadIdx.x >> 5;
    #pragma unroll
    for (int r = ty; r < 32; r += 8)
        if (k0 + r < K && n0 + tx < N)
            tile[r][tx] = src[(size_t)(k0 + r) * N + n0 + tx];
    __syncthreads();
    #pragma unroll
    for (int r = ty; r < 32; r += 8)
        if (n0 + r < N && k0 + tx < K)
            dst[(size_t)(n0 + r) * K + k0 + tx] = f2b(tile[tx][r]);
}

// ---------------- per-layer 4-weight transpose-convert, tight 1D grid ----------------
// tiles: qkv 24x72=1728, proj 24x24=576, w1 24x96=2304, w2 96x24=2304 -> 6912 total
__global__ __launch_bounds__(256) void transpose4_kernel(
    const float* __restrict__ qkvw, const float* __restrict__ projw,
    const float* __restrict__ w1, const float* __restrict__ w2,
    ushort* __restrict__ dq, ushort* __restrict__ dp,
    ushort* __restrict__ d1, ushort* __restrict__ d2)
{
    int tile = blockIdx.x;
    const float* src; ushort* dst; int N, kt, nt;
    if (tile < 1728)      { src = qkvw; dst = dq; N = 2304; kt = tile / 72; nt = tile % 72; }
    else if (tile < 2304) { tile -= 1728; src = projw; dst = dp; N = 768; kt = tile / 24; nt = tile % 24; }
    else if (tile < 4608) { tile -= 2304; src = w1; dst = d1; N = 3072; kt = tile / 96; nt = tile % 96; }
    else                  { tile -= 4608; src = w2; dst = d2; N = 768; kt = tile / 24; nt = tile % 24; }
    int K = (dst == d2) ? 3072 : 768;
    int k0 = kt * 32, n0 = nt * 32;
    __shared__ float tilebuf[32][33];
    int tx = threadIdx.x & 31, ty = threadIdx.x >> 5;
    #pragma unroll
    for (int r = ty; r < 32; r += 8)
        tilebuf[r][tx] = src[(size_t)(k0 + r) * N + n0 + tx];
    __syncthreads();
    #pragma unroll
    for (int r = ty; r < 32; r += 8)
        dst[(size_t)(n0 + r) * K + k0 + tx] = f2b(tilebuf[tx][r]);
}

// ---------------- bf16 MFMA GEMM: A (M,K) bf16 @ B^T (N,K) bf16 -> out ----------------
// flags: 1 = exact gelu, 2 = bf16 output. K % 32 == 0 required.
#define TM 128
#define TN 128
__global__ __launch_bounds__(256) void gemm_bf16(
    const ushort* __restrict__ A, const ushort* __restrict__ B,
    void* __restrict__ outp, const float* __restrict__ bias,
    const float* __restrict__ residual, int M, int N, int K, int flags)
{
    __shared__ ushort As[4][128][8];
    __shared__ ushort Bs[4][128][8];
    const int tid = threadIdx.x;
    const int wave = tid >> 6, lane = tid & 63;
    const int br = blockIdx.y * TM, bc = blockIdx.x * TN;
    const int wm = (wave >> 1) * 64, wn = (wave & 1) * 64;

    const int hA0 = tid >> 7, rA0 = tid & 127;
    const int hA1 = (tid + 256) >> 7;
    const ushort* pA0 = A + (size_t)min(br + rA0, M - 1) * K + hA0 * 8;
    const ushort* pA1 = A + (size_t)min(br + rA0, M - 1) * K + hA1 * 8;
    const ushort* pB0 = B + (size_t)min(bc + rA0, N - 1) * K + hA0 * 8;
    const ushort* pB1 = B + (size_t)min(bc + rA0, N - 1) * K + hA1 * 8;
    ushort* sA0 = &As[0][0][0] + (size_t)(wave * 64) * 8;
    ushort* sA1 = &As[0][0][0] + (size_t)(256 + wave * 64) * 8;
    ushort* sB0 = &Bs[0][0][0] + (size_t)(wave * 64) * 8;
    ushort* sB1 = &Bs[0][0][0] + (size_t)(256 + wave * 64) * 8;

    f32x4 acc[4][4];
    #pragma unroll
    for (int i = 0; i < 4; ++i)
        #pragma unroll
        for (int j = 0; j < 4; ++j) acc[i][j] = (f32x4){0.f, 0.f, 0.f, 0.f};

    const int h = lane >> 4, m16 = lane & 15;
    const int nk = K >> 5;
    for (int kt = 0; kt < nk; ++kt) {
        __syncthreads();
        gld16(pA0, sA0); gld16(pA1, sA1);
        gld16(pB0, sB0); gld16(pB1, sB1);
        pA0 += 32; pA1 += 32; pB0 += 32; pB1 += 32;
        __syncthreads();
        short8 af[4], bfr[4];
        #pragma unroll
        for (int i = 0; i < 4; ++i) af[i]  = *(const short8*)&As[h][wm + i * 16 + m16][0];
        #pragma unroll
        for (int j = 0; j < 4; ++j) bfr[j] = *(const short8*)&Bs[h][wn + j * 16 + m16][0];
        #pragma unroll
        for (int i = 0; i < 4; ++i)
            #pragma unroll
            for (int j = 0; j < 4; ++j)
                acc[i][j] = __builtin_amdgcn_mfma_f32_16x16x32_bf16(af[i], bfr[j], acc[i][j], 0, 0, 0);
    }

    const bool obf = (flags & 2) != 0, gelu = (flags & 1) != 0;
    const int q = lane >> 4, cx = lane & 15;
    #pragma unroll
    for (int j = 0; j < 4; ++j) {
        int gc = bc + wn + j * 16 + cx;
        if (gc >= N) continue;
        float bv = bias ? bias[gc] : 0.f;
        #pragma unroll
        for (int i = 0; i < 4; ++i) {
            #pragma unroll
            for (int r = 0; r < 4; ++r) {
                int gr = br + wm + i * 16 + q * 4 + r;
                if (gr >= M) continue;
                float v = acc[i][j][r] + bv;
                if (gelu) v = 0.5f * v * (1.f + erff(v * 0.70710678118654752f));
                size_t off = (size_t)gr * N + gc;
                if (residual) v += residual[off];
                if (obf) ((ushort*)outp)[off] = f2b(v);
                else     ((float*)outp)[off] = v;
            }
        }
    }
}

// ---------------- LayerNorm: fp32 in -> bf16 out, rows x 768 ----------------
__global__ __launch_bounds__(256) void ln_kernel(
    const float* __restrict__ in, ushort* __restrict__ out,
    const float* __restrict__ w, const float* __restrict__ b, long in_stride)
{
    int row = blockIdx.x;
    const float* xr = in + (size_t)row * in_stride;
    ushort* orow = out + (size_t)row * 768;
    int tid = threadIdx.x;
    float vals[3];
    float s = 0.f, s2 = 0.f;
    #pragma unroll
    for (int l = 0; l < 3; ++l) {
        float v = xr[tid + l * 256];
        vals[l] = v; s += v; s2 += v * v;
    }
    __shared__ float sh[256];
    __shared__ float stats[2];
    sh[tid] = s; __syncthreads();
    for (int o = 128; o > 0; o >>= 1) { if (tid < o) sh[tid] += sh[tid + o]; __syncthreads(); }
    if (tid == 0) stats[0] = sh[0];
    __syncthreads();
    sh[tid] = s2; __syncthreads();
    for (int o = 128; o > 0; o >>= 1) { if (tid < o) sh[tid] += sh[tid + o]; __syncthreads(); }
    if (tid == 0) stats[1] = sh[0];
    __syncthreads();
    float mean = stats[0] * (1.f / 768.f);
    float var = stats[1] * (1.f / 768.f) - mean * mean;
    float rstd = rsqrtf(var + 1e-5f);
    #pragma unroll
    for (int l = 0; l < 3; ++l) {
        int c = tid + l * 256;
        orow[c] = f2b((vals[l] - mean) * rstd * w[c] + b[c]);
    }
}

// ---------------- Attention via MFMA: dense 197(+pad to 224) keys, masked softmax ----
// Block = (head, batch, qsplit of 2). 4 waves, each owns 16-query tiles.
// S = Q@K^T with mfma_16x16x32 (Q,K frags straight from global/L2).
// Mask as register select (-1e30), 16-lane shfl_xor softmax, P->bf16->LDS
// (A-frag relayout), O = P@V with V^T staged in LDS.
// LDS strides 232 ushorts = 464B: 16B-aligned rows for ds_read_b128, row-step
// 20 banks mod 32 -> <=2-way conflicts (free).
#define VST 232
__global__ __launch_bounds__(256) void attn_kernel(
    const ushort* __restrict__ qkv, ushort* __restrict__ out)
{
    const int h = blockIdx.x, b = blockIdx.y, zs = blockIdx.z;
    __shared__ ushort Vsh[64][VST];        // V^T: Vsh[d][k]
    __shared__ ushort Psh[4][16][VST];     // per-wave P: Psh[w][q][k]
    const int tid = threadIdx.x, wave = tid >> 6, lane = tid & 63;
    const size_t base = (size_t)b * Nn_TOK * 2304 + (size_t)h * 64;

    // zero V^T (padding keys 197..223 must contribute 0, not garbage/NaN)
    {
        short8* vf = (short8*)&Vsh[0][0];
        for (int i = tid; i < 64 * VST / 8; i += 256)
            vf[i] = (short8){0, 0, 0, 0, 0, 0, 0, 0};
    }
    __syncthreads();
    // stage V^T: Vsh[d][n] = V[n][d]; coalesced u32 global reads
    for (int idx = tid; idx < Nn_TOK * 32; idx += 256) {
        int n = idx >> 5, d2 = (idx & 31) * 2;
        unsigned u = *(const unsigned*)(qkv + base + 1536 + (size_t)n * 2304 + d2);
        Vsh[d2][n]     = (ushort)(u & 0xffffu);
        Vsh[d2 + 1][n] = (ushort)(u >> 16);
    }
    // zero own wave's P pad region, cols [208,224) (key tile 13 stays 0 forever)
    *(unsigned long long*)&Psh[wave][lane >> 2][208 + (lane & 3) * 4] = 0ull;
    __syncthreads();

    const int kcol = lane & 15, lhi = lane >> 4;
    // per-lane key geometry (independent of query tile)
    int rk[14], ck[14]; bool kin[14], kwin[14];
    #pragma unroll
    for (int kt = 0; kt < 14; ++kt) {
        int k = kt * 16 + kcol;
        kin[kt]  = (k < Nn_TOK);
        kwin[kt] = (k >= 1) && (k < Nn_TOK);
        int km1 = k - 1;
        rk[kt] = km1 / 14;
        ck[kt] = km1 - rk[kt] * 14;
    }
    const bool kcls = (kcol == 0);

    const int tlo = zs ? 7 : 0, thi = zs ? 13 : 7;
    for (int qt = tlo + wave; qt < thi; qt += 4) {
        const int qbase = qt * 16;
        // Q fragments, held in registers across the whole key loop
        const int qrow = qbase + kcol;
        const ushort* qp = qkv + base + (size_t)min(qrow, Nn_TOK - 1) * 2304 + lhi * 8;
        const short8 qf0 = *(const short8*)qp;
        const short8 qf1 = *(const short8*)(qp + 32);

        // S = Q @ K^T : rows = 16 queries, cols = 224 keys (14 tiles)
        f32x4 S[14];
        #pragma unroll
        for (int kt = 0; kt < 14; ++kt) {
            int krow = min(kt * 16 + kcol, Nn_TOK - 1);
            const ushort* kp = qkv + base + 768 + (size_t)krow * 2304 + lhi * 8;
            short8 kf0 = *(const short8*)kp;
            short8 kf1 = *(const short8*)(kp + 32);
            f32x4 s = (f32x4){0.f, 0.f, 0.f, 0.f};
            s = __builtin_amdgcn_mfma_f32_16x16x32_bf16(qf0, kf0, s, 0, 0, 0);
            s = __builtin_amdgcn_mfma_f32_16x16x32_bf16(qf1, kf1, s, 0, 0, 0);
            S[kt] = s;
        }

        // mask: rows held by this lane are q = qbase + lhi*4 + r, col = kt*16 + kcol
        int rq_[4], cq_[4]; bool qc_[4];
        #pragma unroll
        for (int r = 0; r < 4; ++r) {
            int q = qbase + lhi * 4 + r;
            qc_[r] = (q == 0);
            int qm1 = q - 1;
            rq_[r] = qm1 / 14;
            cq_[r] = qm1 - rq_[r] * 14;
        }
        #pragma unroll
        for (int kt = 0; kt < 14; ++kt)
            #pragma unroll
            for (int r = 0; r < 4; ++r) {
                unsigned dr = (unsigned)(rq_[r] - rk[kt] + 3);
                unsigned dc = (unsigned)(cq_[r] - ck[kt] + 3);
                bool ok = (kwin[kt] && dr <= 6u && dc <= 6u)
                          || (qc_[r] && kin[kt]) || (kt == 0 && kcls);
                S[kt][r] = ok ? S[kt][r] : -1e30f;
            }

        // softmax per query row (16 lanes of a row-group hold the 16 tile-cols)
        float mx[4] = {-1e30f, -1e30f, -1e30f, -1e30f};
        #pragma unroll
        for (int kt = 0; kt < 14; ++kt)
            #pragma unroll
            for (int r = 0; r < 4; ++r) mx[r] = fmaxf(mx[r], S[kt][r]);
        #pragma unroll
        for (int r = 0; r < 4; ++r) {
            #pragma unroll
            for (int o = 8; o > 0; o >>= 1) mx[r] = fmaxf(mx[r], __shfl_xor(mx[r], o));
        }
        float ls[4] = {0.f, 0.f, 0.f, 0.f};
        #pragma unroll
        for (int kt = 0; kt < 14; ++kt)
            #pragma unroll
            for (int r = 0; r < 4; ++r) {
                float p = __expf((S[kt][r] - mx[r]) * 0.125f);  // scale folded into exp
                S[kt][r] = p; ls[r] += p;
            }
        #pragma unroll
        for (int r = 0; r < 4; ++r) {
            #pragma unroll
            for (int o = 8; o > 0; o >>= 1) ls[r] += __shfl_xor(ls[r], o);
            ls[r] = 1.f / ls[r];
        }

        // normalized P -> bf16 -> Psh (tiles 0..12; tile 13 region is zero)
        #pragma unroll
        for (int kt = 0; kt < 13; ++kt)
            #pragma unroll
            for (int r = 0; r < 4; ++r)
                Psh[wave][lhi * 4 + r][kt * 16 + kcol] = f2b(S[kt][r] * ls[r]);

        // O = P @ V : A-frag from Psh, B-frag (= V^T rows) from Vsh
        f32x4 O[4];
        #pragma unroll
        for (int j = 0; j < 4; ++j) O[j] = (f32x4){0.f, 0.f, 0.f, 0.f};
        #pragma unroll
        for (int ks = 0; ks < 7; ++ks) {
            short8 pf = *(const short8*)&Psh[wave][kcol][ks * 32 + lhi * 8];
            #pragma unroll
            for (int j = 0; j < 4; ++j) {
                short8 vfr = *(const short8*)&Vsh[j * 16 + kcol][ks * 32 + lhi * 8];
                O[j] = __builtin_amdgcn_mfma_f32_16x16x32_bf16(pf, vfr, O[j], 0, 0, 0);
            }
        }

        // write rows q = qbase + lhi*4 + r, cols h*64 + j*16 + kcol
        #pragma unroll
        for (int r = 0; r < 4; ++r) {
            int q = qbase + lhi * 4 + r;
            if (q < Nn_TOK) {
                size_t orow = ((size_t)b * Nn_TOK + q) * 768 + (size_t)h * 64;
                #pragma unroll
                for (int j = 0; j < 4; ++j)
                    out[orow + j * 16 + kcol] = f2b(O[j][r]);
            }
        }
    }
}

extern "C" void kernel_launch(void* const* d_in, const int* in_sizes, int n_in,
                              void* d_out, int out_size, void* d_ws, size_t ws_size,
                              hipStream_t stream) {
    const float* x        = (const float*)d_in[0];
    const float* patch_w  = (const float*)d_in[1];
    const float* patch_b  = (const float*)d_in[2];
    const float* cls_tok  = (const float*)d_in[3];
    const float* pos_emb  = (const float*)d_in[4];
    const float* ln1_w    = (const float*)d_in[5];
    const float* ln1_b    = (const float*)d_in[6];
    const float* qkv_w    = (const float*)d_in[7];
    const float* proj_w   = (const float*)d_in[8];
    const float* proj_b   = (const float*)d_in[9];
    const float* ln2_w    = (const float*)d_in[10];
    const float* ln2_b    = (const float*)d_in[11];
    const float* mlp_w1   = (const float*)d_in[12];
    const float* mlp_b1   = (const float*)d_in[13];
    const float* mlp_w2   = (const float*)d_in[14];
    const float* mlp_b2   = (const float*)d_in[15];
    const float* norm_w   = (const float*)d_in[16];
    const float* norm_b   = (const float*)d_in[17];
    const float* head_w   = (const float*)d_in[18];
    const float* head_b   = (const float*)d_in[19];
    float* out = (float*)d_out;

    char* ws = (char*)d_ws;
    float*  t     = (float*)ws;                        // 6304x768 fp32
    float*  pbuf  = (float*)(ws + 19365888);           // 6272x768 fp32
    ushort* abuf  = (ushort*)(ws + 38633472);          // 6304x768 bf16
    ushort* qbuf  = (ushort*)(ws + 48316416);          // 6304x2304 bf16
    ushort* hbuf  = (ushort*)(ws + 77365248);          // 6304x3072 bf16
    ushort* wq    = (ushort*)(ws + 116097024);         // 2304x768
    ushort* wp    = wq + 1769472;                      // 768x768
    ushort* w1t   = wp + 589824;                       // 3072x768
    ushort* w2t   = w1t + 2359296;                     // 768x3072
    ushort* pwbuf = (ushort*)(ws + 130252800);         // 768x768
    ushort* hwbuf = (ushort*)(ws + 131432448);         // 1000x768

    const int M_tok = Bb * Nn_TOK;  // 6304

    {
        size_t total = (size_t)Bb * 196 * 768;
        im2col_kernel<<<dim3((total + 255) / 256), 256, 0, stream>>>(x, abuf);
    }
    cvt_kernel<<<dim3((589824 + 255) / 256), 256, 0, stream>>>(patch_w, pwbuf, 589824);
    transpose_one<<<dim3(24, 32), 256, 0, stream>>>(head_w, hwbuf, 768, NC);
    gemm_bf16<<<dim3(6, 49), 256, 0, stream>>>(abuf, pwbuf, pbuf, patch_b, nullptr, Bb * 196, Cc, Cc, 0);
    {
        size_t total = (size_t)M_tok * 768;
        assemble_kernel<<<dim3((total + 255) / 256), 256, 0, stream>>>(pbuf, cls_tok, pos_emb, t);
    }

    for (int i = 0; i < Dn; ++i) {
        transpose4_kernel<<<dim3(6912), 256, 0, stream>>>(
            qkv_w + (size_t)i * Cc * 3 * Cc, proj_w + (size_t)i * Cc * Cc,
            mlp_w1 + (size_t)i * Cc * HID, mlp_w2 + (size_t)i * HID * Cc,
            wq, wp, w1t, w2t);
        ln_kernel<<<dim3(M_tok), 256, 0, stream>>>(t, abuf, ln1_w + i * Cc, ln1_b + i * Cc, Cc);
        gemm_bf16<<<dim3(18, 50), 256, 0, stream>>>(abuf, wq, qbuf, nullptr, nullptr, M_tok, 3 * Cc, Cc, 2);
        attn_kernel<<<dim3(NHh, Bb, 2), 256, 0, stream>>>(qbuf, abuf);
        gemm_bf16<<<dim3(6, 50), 256, 0, stream>>>(abuf, wp, t, proj_b + i * Cc, t, M_tok, Cc, Cc, 0);
        ln_kernel<<<dim3(M_tok), 256, 0, stream>>>(t, abuf, ln2_w + i * Cc, ln2_b + i * Cc, Cc);
        gemm_bf16<<<dim3(24, 50), 256, 0, stream>>>(abuf, w1t, hbuf, mlp_b1 + i * HID, nullptr, M_tok, HID, Cc, 3);
        gemm_bf16<<<dim3(6, 50), 256, 0, stream>>>(hbuf, w2t, t, mlp_b2 + i * Cc, t, M_tok, Cc, HID, 0);
    }

    ln_kernel<<<dim3(Bb), 256, 0, stream>>>(t, abuf, norm_w, norm_b, (long)Nn_TOK * Cc);
    gemm_bf16<<<dim3(8, 1), 256, 0, stream>>>(abuf, hwbuf, out, head_b, nullptr, Bb, NC, Cc, 0);
}

// Round 2
// 5474.338 us; speedup vs baseline: 1.3336x; 1.0458x over previous
//
#include <hip/hip_runtime.h>
#include <hip/hip_bf16.h>
#include <math.h>

#define Dn 12
#define Cc 768
#define NHh 12
#define HD 64
#define Gg 14
#define Nn_TOK 197
#define HID 3072
#define NC 1000
#define Bb 32

typedef __attribute__((ext_vector_type(8))) short short8;
typedef __attribute__((ext_vector_type(4))) float f32x4;

__device__ __forceinline__ ushort f2b(float v) {
    union { float f; unsigned u; } x; x.f = v;
    unsigned r = x.u + 0x7fff + ((x.u >> 16) & 1);
    return (ushort)(r >> 16);
}
__device__ __forceinline__ float b2f(ushort v) {
    union { unsigned u; float f; } x; x.u = ((unsigned)v) << 16; return x.f;
}
__device__ __forceinline__ void gld16(const void* g, void* s) {
    __builtin_amdgcn_global_load_lds(
        (const __attribute__((address_space(1))) void*)g,
        (__attribute__((address_space(3))) void*)s, 16, 0, 0);
}

// ---------------- im2col: x (B,3,224,224) fp32 -> xp (B,196,768) bf16 ----------------
__global__ void im2col_kernel(const float* __restrict__ x, ushort* __restrict__ xp) {
    size_t idx = (size_t)blockIdx.x * 256 + threadIdx.x;
    const size_t total = (size_t)Bb * 196 * 768;
    if (idx >= total) return;
    int j = idx % 768;
    size_t t0 = idx / 768;
    int g = t0 % 196;
    int b = t0 / 196;
    int ch = j / 256, rem = j % 256, pr = rem / 16, pc = rem % 16;
    int gr = g / Gg, gc = g % Gg;
    int row = gr * 16 + pr, col = gc * 16 + pc;
    xp[idx] = f2b(x[(((size_t)b * 3 + ch) * 224 + row) * 224 + col]);
}

// ---------------- assemble t = concat(cls, patches) + pos (fp32) ----------------
__global__ void assemble_kernel(const float* __restrict__ pe, const float* __restrict__ cls,
                                const float* __restrict__ pos, float* __restrict__ t) {
    size_t idx = (size_t)blockIdx.x * 256 + threadIdx.x;
    const size_t total = (size_t)Bb * Nn_TOK * 768;
    if (idx >= total) return;
    int c = idx % 768;
    size_t r = idx / 768;
    int n = r % Nn_TOK, b = r / Nn_TOK;
    float v;
    if (n == 0) v = cls[c];
    else       v = pe[((size_t)b * 196 + (n - 1)) * 768 + c];
    t[idx] = v + pos[(size_t)n * 768 + c];
}

// ---------------- elementwise fp32 -> bf16 convert ----------------
__global__ void cvt_kernel(const float* __restrict__ src, ushort* __restrict__ dst, int n) {
    int idx = blockIdx.x * 256 + threadIdx.x;
    if (idx < n) dst[idx] = f2b(src[idx]);
}

// ---------------- tiled transpose-convert: src (K,N) fp32 -> dst (N,K) bf16 ----------------
__global__ __launch_bounds__(256) void transpose_one(const float* __restrict__ src,
                                                     ushort* __restrict__ dst, int K, int N) {
    int k0 = blockIdx.x * 32, n0 = blockIdx.y * 32;
    __shared__ float tile[32][33];
    int tx = threadIdx.x & 31, ty = threadIdx.x >> 5;
    #pragma unroll
    for (int r = ty; r < 32; r += 8)
        if (k0 + r < K && n0 + tx < N)
            tile[r][tx] = src[(size_t)(k0 + r) * N + n0 + tx];
    __syncthreads();
    #pragma unroll
    for (int r = ty; r < 32; r += 8)
        if (n0 + r < N && k0 + tx < K)
            dst[(size_t)(n0 + r) * K + k0 + tx] = f2b(tile[tx][r]);
}

// ---------------- per-layer 4-weight transpose-convert, tight 1D grid ----------------
// tiles: qkv 24x72=1728, proj 24x24=576, w1 24x96=2304, w2 96x24=2304 -> 6912 total
__global__ __launch_bounds__(256) void transpose4_kernel(
    const float* __restrict__ qkvw, const float* __restrict__ projw,
    const float* __restrict__ w1, const float* __restrict__ w2,
    ushort* __restrict__ dq, ushort* __restrict__ dp,
    ushort* __restrict__ d1, ushort* __restrict__ d2)
{
    int tile = blockIdx.x;
    const float* src; ushort* dst; int N, kt, nt;
    if (tile < 1728)      { src = qkvw; dst = dq; N = 2304; kt = tile / 72; nt = tile % 72; }
    else if (tile < 2304) { tile -= 1728; src = projw; dst = dp; N = 768; kt = tile / 24; nt = tile % 24; }
    else if (tile < 4608) { tile -= 2304; src = w1; dst = d1; N = 3072; kt = tile / 96; nt = tile % 96; }
    else                  { tile -= 4608; src = w2; dst = d2; N = 768; kt = tile / 24; nt = tile % 24; }
    int K = (dst == d2) ? 3072 : 768;
    int k0 = kt * 32, n0 = nt * 32;
    __shared__ float tilebuf[32][33];
    int tx = threadIdx.x & 31, ty = threadIdx.x >> 5;
    #pragma unroll
    for (int r = ty; r < 32; r += 8)
        tilebuf[r][tx] = src[(size_t)(k0 + r) * N + n0 + tx];
    __syncthreads();
    #pragma unroll
    for (int r = ty; r < 32; r += 8)
        dst[(size_t)(n0 + r) * K + k0 + tx] = f2b(tilebuf[tx][r]);
}

// ---------------- bf16 MFMA GEMM: A (M,K) bf16 @ B^T (N,K) bf16 -> out ----------------
// flags: 1 = exact gelu, 2 = bf16 output. K % 32 == 0 required.
// Double-buffered LDS + counted vmcnt prefetch pipeline (T3/T4 minimum recipe)
// + bijective XCD-aware block swizzle (T1, m204).
#define TM 128
#define TN 128
__global__ __launch_bounds__(256) void gemm_bf16(
    const ushort* __restrict__ A, const ushort* __restrict__ B,
    void* __restrict__ outp, const float* __restrict__ bias,
    const float* __restrict__ residual, int M, int N, int K, int flags)
{
    __shared__ ushort As[2][4][128][8];   // [buf][k-chunk of 8][row][8]
    __shared__ ushort Bs[2][4][128][8];
    const int tid = threadIdx.x;
    const int wave = tid >> 6, lane = tid & 63;

    // bijective XCD swizzle: each XCD gets a contiguous chunk of row-major block ids
    const int nwg = gridDim.x * gridDim.y;
    const int orig = blockIdx.y * gridDim.x + blockIdx.x;
    const int xcd = orig & 7, loc = orig >> 3;
    const int q8 = nwg >> 3, r8 = nwg & 7;
    const int swz = (xcd < r8 ? xcd * (q8 + 1) : r8 * (q8 + 1) + (xcd - r8) * q8) + loc;
    const int bx = swz % gridDim.x, by = swz / gridDim.x;

    const int br = by * TM, bc = bx * TN;
    const int wm = (wave >> 1) * 64, wn = (wave & 1) * 64;

    const int hA0 = tid >> 7, rA0 = tid & 127;
    const int hA1 = (tid + 256) >> 7;
    const ushort* pA0 = A + (size_t)min(br + rA0, M - 1) * K + hA0 * 8;
    const ushort* pA1 = A + (size_t)min(br + rA0, M - 1) * K + hA1 * 8;
    const ushort* pB0 = B + (size_t)min(bc + rA0, N - 1) * K + hA0 * 8;
    const ushort* pB1 = B + (size_t)min(bc + rA0, N - 1) * K + hA1 * 8;
    ushort* sA0 = &As[0][0][0][0] + (size_t)(wave * 64) * 8;
    ushort* sA1 = &As[0][0][0][0] + (size_t)(256 + wave * 64) * 8;
    ushort* sB0 = &Bs[0][0][0][0] + (size_t)(wave * 64) * 8;
    ushort* sB1 = &Bs[0][0][0][0] + (size_t)(256 + wave * 64) * 8;
    const size_t BUFO = 4096;  // ushorts per buffer (4*128*8)

    f32x4 acc[4][4];
    #pragma unroll
    for (int i = 0; i < 4; ++i)
        #pragma unroll
        for (int j = 0; j < 4; ++j) acc[i][j] = (f32x4){0.f, 0.f, 0.f, 0.f};

    const int h = lane >> 4, m16 = lane & 15;
    const int nk = K >> 5;

    // prologue: stage tile 0 into buffer 0
    gld16(pA0, sA0); gld16(pA1, sA1);
    gld16(pB0, sB0); gld16(pB1, sB1);

    for (int kt = 0; kt < nk; ++kt) {
        const int cur = kt & 1;
        if (kt + 1 < nk) {
            // issue next tile's loads into the other buffer (stay in flight across barrier)
            const size_t ko = (size_t)(kt + 1) * 32;
            const size_t bo = (size_t)((kt + 1) & 1) * BUFO;
            gld16(pA0 + ko, sA0 + bo); gld16(pA1 + ko, sA1 + bo);
            gld16(pB0 + ko, sB0 + bo); gld16(pB1 + ko, sB1 + bo);
            asm volatile("s_waitcnt vmcnt(4)" ::: "memory");  // wait tile kt only
        } else {
            asm volatile("s_waitcnt vmcnt(0)" ::: "memory");
        }
        __builtin_amdgcn_s_barrier();

        short8 af[4], bfr[4];
        #pragma unroll
        for (int i = 0; i < 4; ++i) af[i]  = *(const short8*)&As[cur][h][wm + i * 16 + m16][0];
        #pragma unroll
        for (int j = 0; j < 4; ++j) bfr[j] = *(const short8*)&Bs[cur][h][wn + j * 16 + m16][0];
        #pragma unroll
        for (int i = 0; i < 4; ++i)
            #pragma unroll
            for (int j = 0; j < 4; ++j)
                acc[i][j] = __builtin_amdgcn_mfma_f32_16x16x32_bf16(af[i], bfr[j], acc[i][j], 0, 0, 0);

        // all ds_reads of buf[cur] must retire before next iter's stage overwrites it
        asm volatile("s_waitcnt lgkmcnt(0)" ::: "memory");
        __builtin_amdgcn_sched_barrier(0);
        __builtin_amdgcn_s_barrier();
    }

    const bool obf = (flags & 2) != 0, gelu = (flags & 1) != 0;
    const int q = lane >> 4, cx = lane & 15;
    #pragma unroll
    for (int j = 0; j < 4; ++j) {
        int gc = bc + wn + j * 16 + cx;
        if (gc >= N) continue;
        float bv = bias ? bias[gc] : 0.f;
        #pragma unroll
        for (int i = 0; i < 4; ++i) {
            #pragma unroll
            for (int r = 0; r < 4; ++r) {
                int gr = br + wm + i * 16 + q * 4 + r;
                if (gr >= M) continue;
                float v = acc[i][j][r] + bv;
                if (gelu) v = 0.5f * v * (1.f + erff(v * 0.70710678118654752f));
                size_t off = (size_t)gr * N + gc;
                if (residual) v += residual[off];
                if (obf) ((ushort*)outp)[off] = f2b(v);
                else     ((float*)outp)[off] = v;
            }
        }
    }
}

// ---------------- LayerNorm: fp32 in -> bf16 out, rows x 768 ----------------
__global__ __launch_bounds__(256) void ln_kernel(
    const float* __restrict__ in, ushort* __restrict__ out,
    const float* __restrict__ w, const float* __restrict__ b, long in_stride)
{
    int row = blockIdx.x;
    const float* xr = in + (size_t)row * in_stride;
    ushort* orow = out + (size_t)row * 768;
    int tid = threadIdx.x;
    float vals[3];
    float s = 0.f, s2 = 0.f;
    #pragma unroll
    for (int l = 0; l < 3; ++l) {
        float v = xr[tid + l * 256];
        vals[l] = v; s += v; s2 += v * v;
    }
    __shared__ float sh[256];
    __shared__ float stats[2];
    sh[tid] = s; __syncthreads();
    for (int o = 128; o > 0; o >>= 1) { if (tid < o) sh[tid] += sh[tid + o]; __syncthreads(); }
    if (tid == 0) stats[0] = sh[0];
    __syncthreads();
    sh[tid] = s2; __syncthreads();
    for (int o = 128; o > 0; o >>= 1) { if (tid < o) sh[tid] += sh[tid + o]; __syncthreads(); }
    if (tid == 0) stats[1] = sh[0];
    __syncthreads();
    float mean = stats[0] * (1.f / 768.f);
    float var = stats[1] * (1.f / 768.f) - mean * mean;
    float rstd = rsqrtf(var + 1e-5f);
    #pragma unroll
    for (int l = 0; l < 3; ++l) {
        int c = tid + l * 256;
        orow[c] = f2b((vals[l] - mean) * rstd * w[c] + b[c]);
    }
}

// ---------------- Attention via MFMA: dense 197(+pad to 224) keys, masked softmax ----
#define VST 232
__global__ __launch_bounds__(256) void attn_kernel(
    const ushort* __restrict__ qkv, ushort* __restrict__ out)
{
    const int h = blockIdx.x, b = blockIdx.y, zs = blockIdx.z;
    __shared__ ushort Vsh[64][VST];        // V^T: Vsh[d][k]
    __shared__ ushort Psh[4][16][VST];     // per-wave P: Psh[w][q][k]
    const int tid = threadIdx.x, wave = tid >> 6, lane = tid & 63;
    const size_t base = (size_t)b * Nn_TOK * 2304 + (size_t)h * 64;

    // zero V^T (padding keys 197..223 must contribute 0, not garbage/NaN)
    {
        short8* vf = (short8*)&Vsh[0][0];
        for (int i = tid; i < 64 * VST / 8; i += 256)
            vf[i] = (short8){0, 0, 0, 0, 0, 0, 0, 0};
    }
    __syncthreads();
    // stage V^T: Vsh[d][n] = V[n][d]; coalesced u32 global reads
    for (int idx = tid; idx < Nn_TOK * 32; idx += 256) {
        int n = idx >> 5, d2 = (idx & 31) * 2;
        unsigned u = *(const unsigned*)(qkv + base + 1536 + (size_t)n * 2304 + d2);
        Vsh[d2][n]     = (ushort)(u & 0xffffu);
        Vsh[d2 + 1][n] = (ushort)(u >> 16);
    }
    // zero own wave's P pad region, cols [208,224) (key tile 13 stays 0 forever)
    *(unsigned long long*)&Psh[wave][lane >> 2][208 + (lane & 3) * 4] = 0ull;
    __syncthreads();

    const int kcol = lane & 15, lhi = lane >> 4;
    // per-lane key geometry (independent of query tile)
    int rk[14], ck[14]; bool kin[14], kwin[14];
    #pragma unroll
    for (int kt = 0; kt < 14; ++kt) {
        int k = kt * 16 + kcol;
        kin[kt]  = (k < Nn_TOK);
        kwin[kt] = (k >= 1) && (k < Nn_TOK);
        int km1 = k - 1;
        rk[kt] = km1 / 14;
        ck[kt] = km1 - rk[kt] * 14;
    }
    const bool kcls = (kcol == 0);

    const int tlo = zs ? 7 : 0, thi = zs ? 13 : 7;
    for (int qt = tlo + wave; qt < thi; qt += 4) {
        const int qbase = qt * 16;
        const int qrow = qbase + kcol;
        const ushort* qp = qkv + base + (size_t)min(qrow, Nn_TOK - 1) * 2304 + lhi * 8;
        const short8 qf0 = *(const short8*)qp;
        const short8 qf1 = *(const short8*)(qp + 32);

        // S = Q @ K^T : rows = 16 queries, cols = 224 keys (14 tiles)
        f32x4 S[14];
        #pragma unroll
        for (int kt = 0; kt < 14; ++kt) {
            int krow = min(kt * 16 + kcol, Nn_TOK - 1);
            const ushort* kp = qkv + base + 768 + (size_t)krow * 2304 + lhi * 8;
            short8 kf0 = *(const short8*)kp;
            short8 kf1 = *(const short8*)(kp + 32);
            f32x4 s = (f32x4){0.f, 0.f, 0.f, 0.f};
            s = __builtin_amdgcn_mfma_f32_16x16x32_bf16(qf0, kf0, s, 0, 0, 0);
            s = __builtin_amdgcn_mfma_f32_16x16x32_bf16(qf1, kf1, s, 0, 0, 0);
            S[kt] = s;
        }

        // mask: rows held by this lane are q = qbase + lhi*4 + r, col = kt*16 + kcol
        int rq_[4], cq_[4]; bool qc_[4];
        #pragma unroll
        for (int r = 0; r < 4; ++r) {
            int q = qbase + lhi * 4 + r;
            qc_[r] = (q == 0);
            int qm1 = q - 1;
            rq_[r] = qm1 / 14;
            cq_[r] = qm1 - rq_[r] * 14;
        }
        #pragma unroll
        for (int kt = 0; kt < 14; ++kt)
            #pragma unroll
            for (int r = 0; r < 4; ++r) {
                unsigned dr = (unsigned)(rq_[r] - rk[kt] + 3);
                unsigned dc = (unsigned)(cq_[r] - ck[kt] + 3);
                bool ok = (kwin[kt] && dr <= 6u && dc <= 6u)
                          || (qc_[r] && kin[kt]) || (kt == 0 && kcls);
                S[kt][r] = ok ? S[kt][r] : -1e30f;
            }

        // softmax per query row (16 lanes of a row-group hold the 16 tile-cols)
        float mx[4] = {-1e30f, -1e30f, -1e30f, -1e30f};
        #pragma unroll
        for (int kt = 0; kt < 14; ++kt)
            #pragma unroll
            for (int r = 0; r < 4; ++r) mx[r] = fmaxf(mx[r], S[kt][r]);
        #pragma unroll
        for (int r = 0; r < 4; ++r) {
            #pragma unroll
            for (int o = 8; o > 0; o >>= 1) mx[r] = fmaxf(mx[r], __shfl_xor(mx[r], o));
        }
        float ls[4] = {0.f, 0.f, 0.f, 0.f};
        #pragma unroll
        for (int kt = 0; kt < 14; ++kt)
            #pragma unroll
            for (int r = 0; r < 4; ++r) {
                float p = __expf((S[kt][r] - mx[r]) * 0.125f);  // scale folded into exp
                S[kt][r] = p; ls[r] += p;
            }
        #pragma unroll
        for (int r = 0; r < 4; ++r) {
            #pragma unroll
            for (int o = 8; o > 0; o >>= 1) ls[r] += __shfl_xor(ls[r], o);
            ls[r] = 1.f / ls[r];
        }

        // normalized P -> bf16 -> Psh (tiles 0..12; tile 13 region is zero)
        #pragma unroll
        for (int kt = 0; kt < 13; ++kt)
            #pragma unroll
            for (int r = 0; r < 4; ++r)
                Psh[wave][lhi * 4 + r][kt * 16 + kcol] = f2b(S[kt][r] * ls[r]);

        // O = P @ V : A-frag from Psh, B-frag (= V^T rows) from Vsh
        f32x4 O[4];
        #pragma unroll
        for (int j = 0; j < 4; ++j) O[j] = (f32x4){0.f, 0.f, 0.f, 0.f};
        #pragma unroll
        for (int ks = 0; ks < 7; ++ks) {
            short8 pf = *(const short8*)&Psh[wave][kcol][ks * 32 + lhi * 8];
            #pragma unroll
            for (int j = 0; j < 4; ++j) {
                short8 vfr = *(const short8*)&Vsh[j * 16 + kcol][ks * 32 + lhi * 8];
                O[j] = __builtin_amdgcn_mfma_f32_16x16x32_bf16(pf, vfr, O[j], 0, 0, 0);
            }
        }

        // write rows q = qbase + lhi*4 + r, cols h*64 + j*16 + kcol
        #pragma unroll
        for (int r = 0; r < 4; ++r) {
            int q = qbase + lhi * 4 + r;
            if (q < Nn_TOK) {
                size_t orow = ((size_t)b * Nn_TOK + q) * 768 + (size_t)h * 64;
                #pragma unroll
                for (int j = 0; j < 4; ++j)
                    out[orow + j * 16 + kcol] = f2b(O[j][r]);
            }
        }
    }
}

extern "C" void kernel_launch(void* const* d_in, const int* in_sizes, int n_in,
                              void* d_out, int out_size, void* d_ws, size_t ws_size,
                              hipStream_t stream) {
    const float* x        = (const float*)d_in[0];
    const float* patch_w  = (const float*)d_in[1];
    const float* patch_b  = (const float*)d_in[2];
    const float* cls_tok  = (const float*)d_in[3];
    const float* pos_emb  = (const float*)d_in[4];
    const float* ln1_w    = (const float*)d_in[5];
    const float* ln1_b    = (const float*)d_in[6];
    const float* qkv_w    = (const float*)d_in[7];
    const float* proj_w   = (const float*)d_in[8];
    const float* proj_b   = (const float*)d_in[9];
    const float* ln2_w    = (const float*)d_in[10];
    const float* ln2_b    = (const float*)d_in[11];
    const float* mlp_w1   = (const float*)d_in[12];
    const float* mlp_b1   = (const float*)d_in[13];
    const float* mlp_w2   = (const float*)d_in[14];
    const float* mlp_b2   = (const float*)d_in[15];
    const float* norm_w   = (const float*)d_in[16];
    const float* norm_b   = (const float*)d_in[17];
    const float* head_w   = (const float*)d_in[18];
    const float* head_b   = (const float*)d_in[19];
    float* out = (float*)d_out;

    char* ws = (char*)d_ws;
    float*  t     = (float*)ws;                        // 6304x768 fp32
    float*  pbuf  = (float*)(ws + 19365888);           // 6272x768 fp32
    ushort* abuf  = (ushort*)(ws + 38633472);          // 6304x768 bf16
    ushort* qbuf  = (ushort*)(ws + 48316416);          // 6304x2304 bf16
    ushort* hbuf  = (ushort*)(ws + 77365248);          // 6304x3072 bf16
    ushort* wq    = (ushort*)(ws + 116097024);         // 2304x768
    ushort* wp    = wq + 1769472;                      // 768x768
    ushort* w1t   = wp + 589824;                       // 3072x768
    ushort* w2t   = w1t + 2359296;                     // 768x3072
    ushort* pwbuf = (ushort*)(ws + 130252800);         // 768x768
    ushort* hwbuf = (ushort*)(ws + 131432448);         // 1000x768

    const int M_tok = Bb * Nn_TOK;  // 6304

    {
        size_t total = (size_t)Bb * 196 * 768;
        im2col_kernel<<<dim3((total + 255) / 256), 256, 0, stream>>>(x, abuf);
    }
    cvt_kernel<<<dim3((589824 + 255) / 256), 256, 0, stream>>>(patch_w, pwbuf, 589824);
    transpose_one<<<dim3(24, 32), 256, 0, stream>>>(head_w, hwbuf, 768, NC);
    gemm_bf16<<<dim3(6, 49), 256, 0, stream>>>(abuf, pwbuf, pbuf, patch_b, nullptr, Bb * 196, Cc, Cc, 0);
    {
        size_t total = (size_t)M_tok * 768;
        assemble_kernel<<<dim3((total + 255) / 256), 256, 0, stream>>>(pbuf, cls_tok, pos_emb, t);
    }

    for (int i = 0; i < Dn; ++i) {
        transpose4_kernel<<<dim3(6912), 256, 0, stream>>>(
            qkv_w + (size_t)i * Cc * 3 * Cc, proj_w + (size_t)i * Cc * Cc,
            mlp_w1 + (size_t)i * Cc * HID, mlp_w2 + (size_t)i * HID * Cc,
            wq, wp, w1t, w2t);
        ln_kernel<<<dim3(M_tok), 256, 0, stream>>>(t, abuf, ln1_w + i * Cc, ln1_b + i * Cc, Cc);
        gemm_bf16<<<dim3(18, 50), 256, 0, stream>>>(abuf, wq, qbuf, nullptr, nullptr, M_tok, 3 * Cc, Cc, 2);
        attn_kernel<<<dim3(NHh, Bb, 2), 256, 0, stream>>>(qbuf, abuf);
        gemm_bf16<<<dim3(6, 50), 256, 0, stream>>>(abuf, wp, t, proj_b + i * Cc, t, M_tok, Cc, Cc, 0);
        ln_kernel<<<dim3(M_tok), 256, 0, stream>>>(t, abuf, ln2_w + i * Cc, ln2_b + i * Cc, Cc);
        gemm_bf16<<<dim3(24, 50), 256, 0, stream>>>(abuf, w1t, hbuf, mlp_b1 + i * HID, nullptr, M_tok, HID, Cc, 3);
        gemm_bf16<<<dim3(6, 50), 256, 0, stream>>>(hbuf, w2t, t, mlp_b2 + i * Cc, t, M_tok, Cc, HID, 0);
    }

    ln_kernel<<<dim3(Bb), 256, 0, stream>>>(t, abuf, norm_w, norm_b, (long)Nn_TOK * Cc);
    gemm_bf16<<<dim3(8, 1), 256, 0, stream>>>(abuf, hwbuf, out, head_b, nullptr, Bb, NC, Cc, 0);
}

// Round 4
// 4817.225 us; speedup vs baseline: 1.5155x; 1.1364x over previous
//
#include <hip/hip_runtime.h>
#include <hip/hip_bf16.h>
#include <math.h>

#define Dn 12
#define Cc 768
#define NHh 12
#define HD 64
#define Gg 14
#define Nn_TOK 197
#define HID 3072
#define NC 1000
#define Bb 32

typedef __attribute__((ext_vector_type(8))) short short8;
typedef __attribute__((ext_vector_type(4))) float f32x4;

__device__ __forceinline__ ushort f2b(float v) {
    union { float f; unsigned u; } x; x.f = v;
    unsigned r = x.u + 0x7fff + ((x.u >> 16) & 1);
    return (ushort)(r >> 16);
}
__device__ __forceinline__ float b2f(ushort v) {
    union { unsigned u; float f; } x; x.u = ((unsigned)v) << 16; return x.f;
}
__device__ __forceinline__ void gld16(const void* g, void* s) {
    __builtin_amdgcn_global_load_lds(
        (const __attribute__((address_space(1))) void*)g,
        (__attribute__((address_space(3))) void*)s, 16, 0, 0);
}

// ---------------- im2col: x (B,3,224,224) fp32 -> xp (B,196,768) bf16 ----------------
__global__ void im2col_kernel(const float* __restrict__ x, ushort* __restrict__ xp) {
    size_t idx = (size_t)blockIdx.x * 256 + threadIdx.x;
    const size_t total = (size_t)Bb * 196 * 768;
    if (idx >= total) return;
    int j = idx % 768;
    size_t t0 = idx / 768;
    int g = t0 % 196;
    int b = t0 / 196;
    int ch = j / 256, rem = j % 256, pr = rem / 16, pc = rem % 16;
    int gr = g / Gg, gc = g % Gg;
    int row = gr * 16 + pr, col = gc * 16 + pc;
    xp[idx] = f2b(x[(((size_t)b * 3 + ch) * 224 + row) * 224 + col]);
}

// ---------------- assemble t = concat(cls, patches) + pos (fp32) ----------------
__global__ void assemble_kernel(const float* __restrict__ pe, const float* __restrict__ cls,
                                const float* __restrict__ pos, float* __restrict__ t) {
    size_t idx = (size_t)blockIdx.x * 256 + threadIdx.x;
    const size_t total = (size_t)Bb * Nn_TOK * 768;
    if (idx >= total) return;
    int c = idx % 768;
    size_t r = idx / 768;
    int n = r % Nn_TOK, b = r / Nn_TOK;
    float v;
    if (n == 0) v = cls[c];
    else       v = pe[((size_t)b * 196 + (n - 1)) * 768 + c];
    t[idx] = v + pos[(size_t)n * 768 + c];
}

// ---------------- elementwise fp32 -> bf16 convert ----------------
__global__ void cvt_kernel(const float* __restrict__ src, ushort* __restrict__ dst, int n) {
    int idx = blockIdx.x * 256 + threadIdx.x;
    if (idx < n) dst[idx] = f2b(src[idx]);
}

// ---------------- tiled transpose-convert: src (K,N) fp32 -> dst (N,K) bf16 ----------------
__global__ __launch_bounds__(256) void transpose_one(const float* __restrict__ src,
                                                     ushort* __restrict__ dst, int K, int N) {
    int k0 = blockIdx.x * 32, n0 = blockIdx.y * 32;
    __shared__ float tile[32][33];
    int tx = threadIdx.x & 31, ty = threadIdx.x >> 5;
    #pragma unroll
    for (int r = ty; r < 32; r += 8)
        if (k0 + r < K && n0 + tx < N)
            tile[r][tx] = src[(size_t)(k0 + r) * N + n0 + tx];
    __syncthreads();
    #pragma unroll
    for (int r = ty; r < 32; r += 8)
        if (n0 + r < N && k0 + tx < K)
            dst[(size_t)(n0 + r) * K + k0 + tx] = f2b(tile[tx][r]);
}

// ---------------- per-layer 4-weight transpose-convert, tight 1D grid ----------------
__global__ __launch_bounds__(256) void transpose4_kernel(
    const float* __restrict__ qkvw, const float* __restrict__ projw,
    const float* __restrict__ w1, const float* __restrict__ w2,
    ushort* __restrict__ dq, ushort* __restrict__ dp,
    ushort* __restrict__ d1, ushort* __restrict__ d2)
{
    int tile = blockIdx.x;
    const float* src; ushort* dst; int N, kt, nt;
    if (tile < 1728)      { src = qkvw; dst = dq; N = 2304; kt = tile / 72; nt = tile % 72; }
    else if (tile < 2304) { tile -= 1728; src = projw; dst = dp; N = 768; kt = tile / 24; nt = tile % 24; }
    else if (tile < 4608) { tile -= 2304; src = w1; dst = d1; N = 3072; kt = tile / 96; nt = tile % 96; }
    else                  { tile -= 4608; src = w2; dst = d2; N = 768; kt = tile / 24; nt = tile % 24; }
    int K = (dst == d2) ? 3072 : 768;
    int k0 = kt * 32, n0 = nt * 32;
    __shared__ float tilebuf[32][33];
    int tx = threadIdx.x & 31, ty = threadIdx.x >> 5;
    #pragma unroll
    for (int r = ty; r < 32; r += 8)
        tilebuf[r][tx] = src[(size_t)(k0 + r) * N + n0 + tx];
    __syncthreads();
    #pragma unroll
    for (int r = ty; r < 32; r += 8)
        dst[(size_t)(n0 + r) * K + k0 + tx] = f2b(tilebuf[tx][r]);
}

// ---------------- 256x256(BN) MFMA GEMM, BK=64, 8 waves, dbuf + counted vmcnt ------
// A (M,K) bf16, B^T (N,K) bf16. flags: 1 = exact gelu, 2 = bf16 out. K % 64 == 0.
// T2 both-sides XOR swizzle: staging pre-swizzles the per-lane GLOBAL source slot
// (slot^row&7) with linear LDS dest (gld16 constraint); ds_read applies the same
// XOR on its 16B-slot -> <=2-way bank conflicts. T4: vmcnt(8/6), never 0 mid-loop.
template<int BN>
__global__ __launch_bounds__(512, 2) void gemm_t(
    const ushort* __restrict__ A, const ushort* __restrict__ B,
    void* __restrict__ outp, const float* __restrict__ bias,
    const float* __restrict__ residual, int M, int N, int K, int flags)
{
    constexpr int JF = BN / 64;       // B frags per wave per k-slice (4 or 2)
    constexpr int BI = BN / 64;       // B staging gld16 per thread per K-tile
    constexpr int ATILE = 256 * 64;   // ushorts per A buffer
    constexpr int BTILE = BN * 64;
    __shared__ ushort As[2 * ATILE];
    __shared__ ushort Bs[2 * BTILE];

    const int tid = threadIdx.x;
    const int wave = tid >> 6, lane = tid & 63;
    const int wr = wave >> 2, wc = wave & 3;   // 2(M) x 4(N) wave grid

    // bijective XCD swizzle (m204)
    const int nwg = gridDim.x * gridDim.y;
    const int orig = blockIdx.y * gridDim.x + blockIdx.x;
    const int xcd = orig & 7, loc = orig >> 3;
    const int q8 = nwg >> 3, r8 = nwg & 7;
    const int swz = (xcd < r8 ? xcd * (q8 + 1) : r8 * (q8 + 1) + (xcd - r8) * q8) + loc;
    const int bx = swz % gridDim.x, by = swz / gridDim.x;
    const int br = by * 256, bc = bx * BN;

    // ---- staging setup: instr i covers rows [i*64, i*64+64), wave w rows w*8..w*8+7
    const int srow = lane >> 3;               // row within wave's 8-row group
    const int sswz = (lane & 7) ^ srow;       // pre-swizzled 16B source slot
    const ushort* pA[4]; const ushort* pB[4];
    ushort* sA[4]; ushort* sB[4];
    #pragma unroll
    for (int i = 0; i < 4; ++i) {
        int row = i * 64 + wave * 8 + srow;
        pA[i] = A + (size_t)min(br + row, M - 1) * K + sswz * 8;
        sA[i] = As + (i * 64 + wave * 8) * 64;
    }
    #pragma unroll
    for (int i = 0; i < BI; ++i) {
        int row = i * 64 + wave * 8 + srow;
        pB[i] = B + (size_t)min(bc + row, N - 1) * K + sswz * 8;
        sB[i] = Bs + (i * 64 + wave * 8) * 64;
    }

    f32x4 acc[8][JF];
    #pragma unroll
    for (int i = 0; i < 8; ++i)
        #pragma unroll
        for (int j = 0; j < JF; ++j) acc[i][j] = (f32x4){0.f, 0.f, 0.f, 0.f};

    const int m16 = lane & 15, h = lane >> 4;
    const int arow = (wr * 128 + m16) * 64;
    const int brow = (wc * (BN / 4) + m16) * 64;
    const int sx = m16 & 7;

    const int nt = K >> 6;
    // prologue: stage tile 0 into buffer 0
    #pragma unroll
    for (int i = 0; i < 4; ++i) gld16(pA[i], sA[i]);
    #pragma unroll
    for (int i = 0; i < BI; ++i) gld16(pB[i], sB[i]);

    for (int t = 0; t < nt; ++t) {
        const int cur = t & 1;
        if (t + 1 < nt) {
            const size_t ko = (size_t)(t + 1) << 6;
            const int nxt = cur ^ 1;
            #pragma unroll
            for (int i = 0; i < 4; ++i) gld16(pA[i] + ko, sA[i] + nxt * ATILE);
            #pragma unroll
            for (int i = 0; i < BI; ++i) gld16(pB[i] + ko, sB[i] + nxt * BTILE);
            if constexpr (BN == 256) asm volatile("s_waitcnt vmcnt(8)" ::: "memory");
            else                     asm volatile("s_waitcnt vmcnt(6)" ::: "memory");
        } else {
            asm volatile("s_waitcnt vmcnt(0)" ::: "memory");
        }
        __builtin_amdgcn_s_barrier();
        __builtin_amdgcn_sched_barrier(0);

        const ushort* Abase = As + cur * ATILE;
        const ushort* Bbase = Bs + cur * BTILE;
        #pragma unroll
        for (int ks = 0; ks < 2; ++ks) {
            const int slot = (((ks << 2) | h) ^ sx) << 3;
            short8 af[8], bf[JF];
            #pragma unroll
            for (int i = 0; i < 8; ++i)
                af[i] = *(const short8*)(Abase + arow + i * 1024 + slot);
            #pragma unroll
            for (int j = 0; j < JF; ++j)
                bf[j] = *(const short8*)(Bbase + brow + j * 1024 + slot);
            __builtin_amdgcn_s_setprio(1);
            #pragma unroll
            for (int i = 0; i < 8; ++i)
                #pragma unroll
                for (int j = 0; j < JF; ++j)
                    acc[i][j] = __builtin_amdgcn_mfma_f32_16x16x32_bf16(af[i], bf[j], acc[i][j], 0, 0, 0);
            __builtin_amdgcn_s_setprio(0);
        }
        asm volatile("s_waitcnt lgkmcnt(0)" ::: "memory");
        __builtin_amdgcn_sched_barrier(0);
        __builtin_amdgcn_s_barrier();
    }

    const bool obf = (flags & 2) != 0, geluf = (flags & 1) != 0;
    #pragma unroll
    for (int j = 0; j < JF; ++j) {
        int gc = bc + wc * (BN / 4) + j * 16 + m16;
        if (gc >= N) continue;
        float bv = bias ? bias[gc] : 0.f;
        #pragma unroll
        for (int i = 0; i < 8; ++i) {
            #pragma unroll
            for (int r = 0; r < 4; ++r) {
                int gr = br + wr * 128 + i * 16 + h * 4 + r;
                if (gr >= M) continue;
                float v = acc[i][j][r] + bv;
                if (geluf) v = 0.5f * v * (1.f + erff(v * 0.70710678118654752f));
                size_t off = (size_t)gr * N + gc;
                if (residual) v += residual[off];
                if (obf) ((ushort*)outp)[off] = f2b(v);
                else     ((float*)outp)[off] = v;
            }
        }
    }
}

// ---------------- LayerNorm: fp32 in -> bf16 out, rows x 768 ----------------
__global__ __launch_bounds__(256) void ln_kernel(
    const float* __restrict__ in, ushort* __restrict__ out,
    const float* __restrict__ w, const float* __restrict__ b, long in_stride)
{
    int row = blockIdx.x;
    const float* xr = in + (size_t)row * in_stride;
    ushort* orow = out + (size_t)row * 768;
    int tid = threadIdx.x;
    float vals[3];
    float s = 0.f, s2 = 0.f;
    #pragma unroll
    for (int l = 0; l < 3; ++l) {
        float v = xr[tid + l * 256];
        vals[l] = v; s += v; s2 += v * v;
    }
    __shared__ float sh[256];
    __shared__ float stats[2];
    sh[tid] = s; __syncthreads();
    for (int o = 128; o > 0; o >>= 1) { if (tid < o) sh[tid] += sh[tid + o]; __syncthreads(); }
    if (tid == 0) stats[0] = sh[0];
    __syncthreads();
    sh[tid] = s2; __syncthreads();
    for (int o = 128; o > 0; o >>= 1) { if (tid < o) sh[tid] += sh[tid + o]; __syncthreads(); }
    if (tid == 0) stats[1] = sh[0];
    __syncthreads();
    float mean = stats[0] * (1.f / 768.f);
    float var = stats[1] * (1.f / 768.f) - mean * mean;
    float rstd = rsqrtf(var + 1e-5f);
    #pragma unroll
    for (int l = 0; l < 3; ++l) {
        int c = tid + l * 256;
        orow[c] = f2b((vals[l] - mean) * rstd * w[c] + b[c]);
    }
}

// ---------------- Attention via MFMA: dense 197(+pad to 224) keys, masked softmax ----
#define VST 232
__global__ __launch_bounds__(256) void attn_kernel(
    const ushort* __restrict__ qkv, ushort* __restrict__ out)
{
    const int h = blockIdx.x, b = blockIdx.y, zs = blockIdx.z;
    __shared__ ushort Vsh[64][VST];        // V^T: Vsh[d][k]
    __shared__ ushort Psh[4][16][VST];     // per-wave P: Psh[w][q][k]
    const int tid = threadIdx.x, wave = tid >> 6, lane = tid & 63;
    const size_t base = (size_t)b * Nn_TOK * 2304 + (size_t)h * 64;

    {
        short8* vf = (short8*)&Vsh[0][0];
        for (int i = tid; i < 64 * VST / 8; i += 256)
            vf[i] = (short8){0, 0, 0, 0, 0, 0, 0, 0};
    }
    __syncthreads();
    for (int idx = tid; idx < Nn_TOK * 32; idx += 256) {
        int n = idx >> 5, d2 = (idx & 31) * 2;
        unsigned u = *(const unsigned*)(qkv + base + 1536 + (size_t)n * 2304 + d2);
        Vsh[d2][n]     = (ushort)(u & 0xffffu);
        Vsh[d2 + 1][n] = (ushort)(u >> 16);
    }
    *(unsigned long long*)&Psh[wave][lane >> 2][208 + (lane & 3) * 4] = 0ull;
    __syncthreads();

    const int kcol = lane & 15, lhi = lane >> 4;
    int rk[14], ck[14]; bool kin[14], kwin[14];
    #pragma unroll
    for (int kt = 0; kt < 14; ++kt) {
        int k = kt * 16 + kcol;
        kin[kt]  = (k < Nn_TOK);
        kwin[kt] = (k >= 1) && (k < Nn_TOK);
        int km1 = k - 1;
        rk[kt] = km1 / 14;
        ck[kt] = km1 - rk[kt] * 14;
    }
    const bool kcls = (kcol == 0);

    const int tlo = zs ? 7 : 0, thi = zs ? 13 : 7;
    for (int qt = tlo + wave; qt < thi; qt += 4) {
        const int qbase = qt * 16;
        const int qrow = qbase + kcol;
        const ushort* qp = qkv + base + (size_t)min(qrow, Nn_TOK - 1) * 2304 + lhi * 8;
        const short8 qf0 = *(const short8*)qp;
        const short8 qf1 = *(const short8*)(qp + 32);

        f32x4 S[14];
        #pragma unroll
        for (int kt = 0; kt < 14; ++kt) {
            int krow = min(kt * 16 + kcol, Nn_TOK - 1);
            const ushort* kp = qkv + base + 768 + (size_t)krow * 2304 + lhi * 8;
            short8 kf0 = *(const short8*)kp;
            short8 kf1 = *(const short8*)(kp + 32);
            f32x4 s = (f32x4){0.f, 0.f, 0.f, 0.f};
            s = __builtin_amdgcn_mfma_f32_16x16x32_bf16(qf0, kf0, s, 0, 0, 0);
            s = __builtin_amdgcn_mfma_f32_16x16x32_bf16(qf1, kf1, s, 0, 0, 0);
            S[kt] = s;
        }

        int rq_[4], cq_[4]; bool qc_[4];
        #pragma unroll
        for (int r = 0; r < 4; ++r) {
            int q = qbase + lhi * 4 + r;
            qc_[r] = (q == 0);
            int qm1 = q - 1;
            rq_[r] = qm1 / 14;
            cq_[r] = qm1 - rq_[r] * 14;
        }
        #pragma unroll
        for (int kt = 0; kt < 14; ++kt)
            #pragma unroll
            for (int r = 0; r < 4; ++r) {
                unsigned dr = (unsigned)(rq_[r] - rk[kt] + 3);
                unsigned dc = (unsigned)(cq_[r] - ck[kt] + 3);
                bool ok = (kwin[kt] && dr <= 6u && dc <= 6u)
                          || (qc_[r] && kin[kt]) || (kt == 0 && kcls);
                S[kt][r] = ok ? S[kt][r] : -1e30f;
            }

        float mx[4] = {-1e30f, -1e30f, -1e30f, -1e30f};
        #pragma unroll
        for (int kt = 0; kt < 14; ++kt)
            #pragma unroll
            for (int r = 0; r < 4; ++r) mx[r] = fmaxf(mx[r], S[kt][r]);
        #pragma unroll
        for (int r = 0; r < 4; ++r) {
            #pragma unroll
            for (int o = 8; o > 0; o >>= 1) mx[r] = fmaxf(mx[r], __shfl_xor(mx[r], o));
        }
        float ls[4] = {0.f, 0.f, 0.f, 0.f};
        #pragma unroll
        for (int kt = 0; kt < 14; ++kt)
            #pragma unroll
            for (int r = 0; r < 4; ++r) {
                float p = __expf((S[kt][r] - mx[r]) * 0.125f);
                S[kt][r] = p; ls[r] += p;
            }
        #pragma unroll
        for (int r = 0; r < 4; ++r) {
            #pragma unroll
            for (int o = 8; o > 0; o >>= 1) ls[r] += __shfl_xor(ls[r], o);
            ls[r] = 1.f / ls[r];
        }

        #pragma unroll
        for (int kt = 0; kt < 13; ++kt)
            #pragma unroll
            for (int r = 0; r < 4; ++r)
                Psh[wave][lhi * 4 + r][kt * 16 + kcol] = f2b(S[kt][r] * ls[r]);

        f32x4 O[4];
        #pragma unroll
        for (int j = 0; j < 4; ++j) O[j] = (f32x4){0.f, 0.f, 0.f, 0.f};
        #pragma unroll
        for (int ks = 0; ks < 7; ++ks) {
            short8 pf = *(const short8*)&Psh[wave][kcol][ks * 32 + lhi * 8];
            #pragma unroll
            for (int j = 0; j < 4; ++j) {
                short8 vfr = *(const short8*)&Vsh[j * 16 + kcol][ks * 32 + lhi * 8];
                O[j] = __builtin_amdgcn_mfma_f32_16x16x32_bf16(pf, vfr, O[j], 0, 0, 0);
            }
        }

        #pragma unroll
        for (int r = 0; r < 4; ++r) {
            int q = qbase + lhi * 4 + r;
            if (q < Nn_TOK) {
                size_t orow = ((size_t)b * Nn_TOK + q) * 768 + (size_t)h * 64;
                #pragma unroll
                for (int j = 0; j < 4; ++j)
                    out[orow + j * 16 + kcol] = f2b(O[j][r]);
            }
        }
    }
}

extern "C" void kernel_launch(void* const* d_in, const int* in_sizes, int n_in,
                              void* d_out, int out_size, void* d_ws, size_t ws_size,
                              hipStream_t stream) {
    const float* x        = (const float*)d_in[0];
    const float* patch_w  = (const float*)d_in[1];
    const float* patch_b  = (const float*)d_in[2];
    const float* cls_tok  = (const float*)d_in[3];
    const float* pos_emb  = (const float*)d_in[4];
    const float* ln1_w    = (const float*)d_in[5];
    const float* ln1_b    = (const float*)d_in[6];
    const float* qkv_w    = (const float*)d_in[7];
    const float* proj_w   = (const float*)d_in[8];
    const float* proj_b   = (const float*)d_in[9];
    const float* ln2_w    = (const float*)d_in[10];
    const float* ln2_b    = (const float*)d_in[11];
    const float* mlp_w1   = (const float*)d_in[12];
    const float* mlp_b1   = (const float*)d_in[13];
    const float* mlp_w2   = (const float*)d_in[14];
    const float* mlp_b2   = (const float*)d_in[15];
    const float* norm_w   = (const float*)d_in[16];
    const float* norm_b   = (const float*)d_in[17];
    const float* head_w   = (const float*)d_in[18];
    const float* head_b   = (const float*)d_in[19];
    float* out = (float*)d_out;

    char* ws = (char*)d_ws;
    float*  t     = (float*)ws;                        // 6304x768 fp32
    float*  pbuf  = (float*)(ws + 19365888);           // 6272x768 fp32
    ushort* abuf  = (ushort*)(ws + 38633472);          // 6304x768 bf16
    ushort* qbuf  = (ushort*)(ws + 48316416);          // 6304x2304 bf16
    ushort* hbuf  = (ushort*)(ws + 77365248);          // 6304x3072 bf16
    ushort* wq    = (ushort*)(ws + 116097024);         // 2304x768
    ushort* wp    = wq + 1769472;                      // 768x768
    ushort* w1t   = wp + 589824;                       // 3072x768
    ushort* w2t   = w1t + 2359296;                     // 768x3072
    ushort* pwbuf = (ushort*)(ws + 130252800);         // 768x768
    ushort* hwbuf = (ushort*)(ws + 131432448);         // 1000x768

    const int M_tok = Bb * Nn_TOK;  // 6304

    {
        size_t total = (size_t)Bb * 196 * 768;
        im2col_kernel<<<dim3((total + 255) / 256), 256, 0, stream>>>(x, abuf);
    }
    cvt_kernel<<<dim3((589824 + 255) / 256), 256, 0, stream>>>(patch_w, pwbuf, 589824);
    transpose_one<<<dim3(24, 32), 256, 0, stream>>>(head_w, hwbuf, 768, NC);
    gemm_t<128><<<dim3(6, 25), 512, 0, stream>>>(abuf, pwbuf, pbuf, patch_b, nullptr, Bb * 196, Cc, Cc, 0);
    {
        size_t total = (size_t)M_tok * 768;
        assemble_kernel<<<dim3((total + 255) / 256), 256, 0, stream>>>(pbuf, cls_tok, pos_emb, t);
    }

    for (int i = 0; i < Dn; ++i) {
        transpose4_kernel<<<dim3(6912), 256, 0, stream>>>(
            qkv_w + (size_t)i * Cc * 3 * Cc, proj_w + (size_t)i * Cc * Cc,
            mlp_w1 + (size_t)i * Cc * HID, mlp_w2 + (size_t)i * HID * Cc,
            wq, wp, w1t, w2t);
        ln_kernel<<<dim3(M_tok), 256, 0, stream>>>(t, abuf, ln1_w + i * Cc, ln1_b + i * Cc, Cc);
        gemm_t<256><<<dim3(9, 25), 512, 0, stream>>>(abuf, wq, qbuf, nullptr, nullptr, M_tok, 3 * Cc, Cc, 2);
        attn_kernel<<<dim3(NHh, Bb, 2), 256, 0, stream>>>(qbuf, abuf);
        gemm_t<128><<<dim3(6, 25), 512, 0, stream>>>(abuf, wp, t, proj_b + i * Cc, t, M_tok, Cc, Cc, 0);
        ln_kernel<<<dim3(M_tok), 256, 0, stream>>>(t, abuf, ln2_w + i * Cc, ln2_b + i * Cc, Cc);
        gemm_t<256><<<dim3(12, 25), 512, 0, stream>>>(abuf, w1t, hbuf, mlp_b1 + i * HID, nullptr, M_tok, HID, Cc, 3);
        gemm_t<128><<<dim3(6, 25), 512, 0, stream>>>(hbuf, w2t, t, mlp_b2 + i * Cc, t, M_tok, Cc, HID, 0);
    }

    ln_kernel<<<dim3(Bb), 256, 0, stream>>>(t, abuf, norm_w, norm_b, (long)Nn_TOK * Cc);
    gemm_t<128><<<dim3(8, 1), 512, 0, stream>>>(abuf, hwbuf, out, head_b, nullptr, Bb, NC, Cc, 0);
}